// Round 1
// baseline (367.211 us; speedup 1.0000x reference)
//
#include <hip/hip_runtime.h>
#include <cstdint>

// Problem constants (B,H,S,D from reference setup_inputs; KP = int(S*0.1))
#define BB 2
#define HH 12
#define SS 1024
#define DD 64
#define KP 102

// ---------------------------------------------------------------------------
// Kernel 1: pack sign bits of q and k rows into uint64 bitmasks.
// One wave (64 lanes) per (b,h,s) row; lane d holds element d.
// bit = 1 iff x > 0  (sign(x)=+1); x<=0 -> -1. dot = 64 - 2*popc(xor).
// ---------------------------------------------------------------------------
__global__ __launch_bounds__(256) void pack_signs_kernel(
    const float* __restrict__ q, const float* __restrict__ k,
    unsigned long long* __restrict__ qbits, unsigned long long* __restrict__ kbits)
{
    int wave = (int)((blockIdx.x * 256 + threadIdx.x) >> 6);
    int lane = (int)(threadIdx.x & 63);
    if (wave >= BB * HH * SS) return;
    float qv = q[(size_t)wave * DD + lane];
    float kv = k[(size_t)wave * DD + lane];
    unsigned long long qm = __ballot(qv > 0.0f);
    unsigned long long km = __ballot(kv > 0.0f);
    if (lane == 0) { qbits[wave] = qm; kbits[wave] = km; }
}

// ---------------------------------------------------------------------------
// Kernel 2: one wave (block of 64) per query.
// Phase A: binary scores for all 1024 keys (16 per lane, t = j*64+lane),
//          LDS histogram over the 65 possible score values.
// Phase B: find threshold bin T and tie budget `need` (stable top-k:
//          all scores > T, plus first `need` ties in ascending key index).
// Phase C: selected keys -> precise score q·k * 0.125 + mask[t], stored in
//          an LDS list (exactly KP entries).
// Phase D: softmax (wave shfl reductions), then lane=dim output accumulation
//          with coalesced v reads.
// ---------------------------------------------------------------------------
__global__ __launch_bounds__(64) void battn_kernel(
    const float* __restrict__ q, const float* __restrict__ k,
    const float* __restrict__ v, const float* __restrict__ mask,
    const unsigned long long* __restrict__ qbits,
    const unsigned long long* __restrict__ kbits,
    float* __restrict__ out)
{
    const int query = (int)blockIdx.x;      // 0 .. B*H*S-1
    const int bh    = query >> 10;          // S = 1024
    const int b     = bh / HH;
    const int lane  = (int)threadIdx.x;

    __shared__ unsigned int hist[65];
    __shared__ float        qsh[DD];
    __shared__ int          sel_t[KP];
    __shared__ float        sel_p[KP];
    __shared__ unsigned int nsel;
    __shared__ int          Tsh, needSh;

    hist[lane] = 0u;
    if (lane == 0) hist[64] = 0u;
    qsh[lane] = q[(size_t)query * DD + lane];
    __syncthreads();

    // ---- Phase A: binary scores + histogram ----
    const unsigned long long qm = qbits[query];
    const unsigned long long* kb = kbits + (size_t)bh * SS;
    int binv[16];
    #pragma unroll
    for (int j = 0; j < 16; ++j) {
        int t = j * 64 + lane;
        unsigned long long km = kb[t];
        int dot = 64 - 2 * __popcll(qm ^ km);       // in [-64, 64], even
        binv[j] = (dot + 64) >> 1;                  // bin 0..64
        atomicAdd(&hist[binv[j]], 1u);
    }
    __syncthreads();

    // ---- Phase B: threshold bin + tie budget ----
    if (lane == 0) {
        int cum = 0, binT = 0;
        for (int bb2 = 64; bb2 >= 0; --bb2) {
            cum += (int)hist[bb2];
            if (cum >= KP) { binT = bb2; break; }
        }
        int cgt = cum - (int)hist[binT];            // count strictly greater
        Tsh = binT;
        needSh = KP - cgt;                          // ties to take (index-asc)
        nsel = 0u;
    }
    __syncthreads();
    const int binT = Tsh;
    const int need = needSh;

    // ---- Phase C: stable selection + precise scores ----
    const float* krows   = k + (size_t)bh * SS * DD;
    const float* maskrow = mask + (size_t)b * SS;
    int tie_base = 0;
    #pragma unroll 1
    for (int j = 0; j < 16; ++j) {
        int t = j * 64 + lane;
        bool isGt  = binv[j] > binT;
        bool isTie = (binv[j] == binT);
        unsigned long long tiemask = __ballot(isTie);
        int myrank = tie_base +
            __popcll(tiemask & ((lane == 0) ? 0ULL : (~0ULL >> (64 - lane))));
        bool take = isGt || (isTie && myrank < need);
        if (take) {
            const float* krow = krows + (size_t)t * DD;
            float dot = 0.0f;
            #pragma unroll
            for (int d0 = 0; d0 < DD; d0 += 4) {
                float4 kv4 = *(const float4*)(krow + d0);
                dot += qsh[d0]     * kv4.x + qsh[d0 + 1] * kv4.y
                     + qsh[d0 + 2] * kv4.z + qsh[d0 + 3] * kv4.w;
            }
            float p = dot * 0.125f + maskrow[t];
            unsigned int idx = atomicAdd(&nsel, 1u);
            sel_t[idx] = t;
            sel_p[idx] = p;
        }
        tie_base += (int)__popcll(tiemask);
    }
    __syncthreads();

    // ---- Phase D: softmax + output ----
    float m = -3.0e38f;
    for (int i = lane; i < KP; i += 64) m = fmaxf(m, sel_p[i]);
    #pragma unroll
    for (int off = 32; off > 0; off >>= 1) m = fmaxf(m, __shfl_xor(m, off));

    float lsum = 0.0f;
    for (int i = lane; i < KP; i += 64) {
        float w = __expf(sel_p[i] - m);
        sel_p[i] = w;                               // own entries only
        lsum += w;
    }
    #pragma unroll
    for (int off = 32; off > 0; off >>= 1) lsum += __shfl_xor(lsum, off);
    __syncthreads();

    const float* vbase = v + (size_t)bh * SS * DD;
    float acc = 0.0f;
    #pragma unroll 2
    for (int i = 0; i < KP; ++i) {
        acc += sel_p[i] * vbase[(size_t)sel_t[i] * DD + lane]; // coalesced in lane
    }
    out[(size_t)query * DD + lane] = acc * __frcp_rn(lsum);
}

extern "C" void kernel_launch(void* const* d_in, const int* in_sizes, int n_in,
                              void* d_out, int out_size, void* d_ws, size_t ws_size,
                              hipStream_t stream) {
    const float* q    = (const float*)d_in[0];
    const float* k    = (const float*)d_in[1];
    const float* v    = (const float*)d_in[2];
    const float* mask = (const float*)d_in[3];
    float* out = (float*)d_out;

    const int rows = BB * HH * SS;                 // 24576
    unsigned long long* qbits = (unsigned long long*)d_ws;
    unsigned long long* kbits = qbits + rows;

    pack_signs_kernel<<<(rows * 64 + 255) / 256, 256, 0, stream>>>(q, k, qbits, kbits);
    battn_kernel<<<rows, 64, 0, stream>>>(q, k, v, mask, qbits, kbits, out);
}

// Round 2
// 165.259 us; speedup vs baseline: 2.2220x; 2.2220x over previous
//
#include <hip/hip_runtime.h>
#include <cstdint>

// Problem constants (B,H,S,D from reference setup_inputs; KP = int(S*0.1))
#define BB 2
#define HH 12
#define SS 1024
#define DD 64
#define KP 102
#define QPB 4   // queries per block (1 wave each)

// ---------------------------------------------------------------------------
// Kernel 1: pack sign bits of k rows into uint64 bitmasks.
// One wave per (b,h,t) row; lane d holds element d. bit=1 iff x>0.
// binary dot = 64 - 2*popc(qm^km).
// ---------------------------------------------------------------------------
__global__ __launch_bounds__(256) void pack_k_kernel(
    const float* __restrict__ k, unsigned long long* __restrict__ kbits)
{
    int wave = (int)((blockIdx.x * 256 + threadIdx.x) >> 6);
    int lane = (int)(threadIdx.x & 63);
    if (wave >= BB * HH * SS) return;
    float kv = k[(size_t)wave * DD + lane];
    unsigned long long km = __ballot(kv > 0.0f);
    if (lane == 0) kbits[wave] = km;
}

// ---------------------------------------------------------------------------
// Kernel 2: 256 threads = 4 waves; wave w handles query blockIdx*4+w.
// All 4 queries share the same (b,h) => stage kbits row-block in LDS once.
// ---------------------------------------------------------------------------
__global__ __launch_bounds__(256) void battn_kernel(
    const float* __restrict__ q, const float* __restrict__ k,
    const float* __restrict__ v, const float* __restrict__ mask,
    const unsigned long long* __restrict__ kbits,
    float* __restrict__ out)
{
    const int tid  = (int)threadIdx.x;
    const int w    = tid >> 6;                    // wave id 0..3
    const int lane = tid & 63;
    const int query = (int)blockIdx.x * QPB + w;  // 0 .. B*H*S-1
    const int bh    = query >> 10;                // S = 1024 (same for all 4 waves)
    const int b     = bh / HH;

    __shared__ unsigned long long kb_sh[SS];      // 8 KB, shared by all waves
    __shared__ float        qsh[QPB][DD];
    __shared__ unsigned int hist[QPB][65];
    __shared__ int          sel_t[QPB][KP];
    __shared__ float        sel_p[QPB][KP];
    __shared__ unsigned int nsel[QPB];
    __shared__ int          TN[QPB][2];           // [0]=binT, [1]=need

    // stage kbits (same bh for whole block) + q row + init
    {
        const unsigned long long* kb = kbits + (size_t)bh * SS;
        #pragma unroll
        for (int it = 0; it < SS / 256; ++it)
            kb_sh[tid + it * 256] = kb[tid + it * 256];
    }
    float qreg = q[(size_t)query * DD + lane];
    qsh[w][lane] = qreg;
    hist[w][lane] = 0u;
    if (lane == 0) { hist[w][64] = 0u; nsel[w] = 0u; }
    __syncthreads();

    // q sign mask computed in-wave (no qbits pass needed)
    const unsigned long long qm = __ballot(qreg > 0.0f);

    // ---- Phase A: binary scores + per-wave histogram ----
    int binv[16];
    #pragma unroll
    for (int j = 0; j < 16; ++j) {
        int t = j * 64 + lane;
        int dot = 64 - 2 * __popcll(qm ^ kb_sh[t]);   // [-64,64], even
        binv[j] = (dot + 64) >> 1;                    // bin 0..64
        atomicAdd(&hist[w][binv[j]], 1u);
    }
    __syncthreads();

    // ---- Phase B: threshold bin + tie budget (stable top-k semantics) ----
    if (lane == 0) {
        int cum = 0, binT = 0;
        for (int bb2 = 64; bb2 >= 0; --bb2) {
            cum += (int)hist[w][bb2];
            if (cum >= KP) { binT = bb2; break; }
        }
        int cgt = cum - (int)hist[w][binT];           // strictly greater
        TN[w][0] = binT;
        TN[w][1] = KP - cgt;                          // ties taken, index-asc
    }
    __syncthreads();
    const int binT = TN[w][0];
    const int need = TN[w][1];

    // ---- Phase C1: stable selection (indices only) ----
    int tie_base = 0;
    #pragma unroll
    for (int j = 0; j < 16; ++j) {
        int t = j * 64 + lane;
        bool isGt  = binv[j] > binT;
        bool isTie = (binv[j] == binT);
        unsigned long long tiemask = __ballot(isTie);
        int myrank = tie_base +
            __popcll(tiemask & ((lane == 0) ? 0ULL : (~0ULL >> (64 - lane))));
        if (isGt || (isTie && myrank < need)) {
            unsigned int idx = atomicAdd(&nsel[w], 1u);
            sel_t[w][idx] = t;
        }
        tie_base += (int)__popcll(tiemask);
    }
    __syncthreads();

    // ---- Phase C2: cooperative precise dots: 8 lanes per key ----
    // group g = lane>>3 handles key sel_t[base+g]; lane reads dims sub*8..+8
    const int sub = lane & 7, g = lane >> 3;
    const float4 qa = *(const float4*)&qsh[w][sub * 8];
    const float4 qb = *(const float4*)&qsh[w][sub * 8 + 4];
    const float* krows   = k + (size_t)bh * SS * DD;
    const float* maskrow = mask + (size_t)b * SS;
    #pragma unroll 1
    for (int base = 0; base < KP; base += 8) {
        int i = base + g;
        bool valid = (i < KP);
        float partial = 0.0f;
        int t = 0;
        if (valid) {
            t = sel_t[w][i];
            const float* krow = krows + (size_t)t * DD + sub * 8;
            float4 ka = *(const float4*)(krow);
            float4 kb4 = *(const float4*)(krow + 4);
            partial = qa.x * ka.x + qa.y * ka.y + qa.z * ka.z + qa.w * ka.w
                    + qb.x * kb4.x + qb.y * kb4.y + qb.z * kb4.z + qb.w * kb4.w;
        }
        partial += __shfl_xor(partial, 1);
        partial += __shfl_xor(partial, 2);
        partial += __shfl_xor(partial, 4);
        if (valid && sub == 0)
            sel_p[w][i] = partial * 0.125f + maskrow[t];
    }
    __syncthreads();

    // ---- Phase D: softmax + output ----
    float m = -3.0e38f;
    for (int i = lane; i < KP; i += 64) m = fmaxf(m, sel_p[w][i]);
    #pragma unroll
    for (int off = 32; off > 0; off >>= 1) m = fmaxf(m, __shfl_xor(m, off));

    float lsum = 0.0f;
    for (int i = lane; i < KP; i += 64) {
        float e = __expf(sel_p[w][i] - m);
        sel_p[w][i] = e;
        lsum += e;
    }
    #pragma unroll
    for (int off = 32; off > 0; off >>= 1) lsum += __shfl_xor(lsum, off);
    __syncthreads();

    const float* vbase = v + (size_t)bh * SS * DD;
    float acc = 0.0f;
    // main loop: batches of 8 with register-staged (t,p) so 8 loads in flight
    #pragma unroll 1
    for (int i0 = 0; i0 + 8 <= KP; i0 += 8) {
        int   tt[8]; float pp[8];
        #pragma unroll
        for (int j = 0; j < 8; ++j) { tt[j] = sel_t[w][i0 + j]; pp[j] = sel_p[w][i0 + j]; }
        #pragma unroll
        for (int j = 0; j < 8; ++j)
            acc += pp[j] * vbase[(size_t)tt[j] * DD + lane];
    }
    {   // tail: KP % 8 = 6
        constexpr int T0 = (KP / 8) * 8;
        int   tt[KP - T0]; float pp[KP - T0];
        #pragma unroll
        for (int j = 0; j < KP - T0; ++j) { tt[j] = sel_t[w][T0 + j]; pp[j] = sel_p[w][T0 + j]; }
        #pragma unroll
        for (int j = 0; j < KP - T0; ++j)
            acc += pp[j] * vbase[(size_t)tt[j] * DD + lane];
    }
    out[(size_t)query * DD + lane] = acc * __frcp_rn(lsum);
}

extern "C" void kernel_launch(void* const* d_in, const int* in_sizes, int n_in,
                              void* d_out, int out_size, void* d_ws, size_t ws_size,
                              hipStream_t stream) {
    const float* q    = (const float*)d_in[0];
    const float* k    = (const float*)d_in[1];
    const float* v    = (const float*)d_in[2];
    const float* mask = (const float*)d_in[3];
    float* out = (float*)d_out;

    const int rows = BB * HH * SS;                 // 24576
    unsigned long long* kbits = (unsigned long long*)d_ws;

    pack_k_kernel<<<(rows * 64 + 255) / 256, 256, 0, stream>>>(k, kbits);
    battn_kernel<<<rows / QPB, 256, 0, stream>>>(q, k, v, mask, kbits, out);
}

// Round 3
// 147.503 us; speedup vs baseline: 2.4895x; 1.1204x over previous
//
#include <hip/hip_runtime.h>
#include <hip/hip_fp16.h>
#include <cstdint>

// Problem constants (B,H,S,D from reference setup_inputs; KP = int(S*0.1))
#define BB 2
#define HH 12
#define SS 1024
#define DD 64
#define KP 102
#define QPB 4   // queries per block (1 wave each)

typedef _Float16 half2v __attribute__((ext_vector_type(2)));
typedef _Float16 half8v __attribute__((ext_vector_type(8)));

// ---------------------------------------------------------------------------
// Kernel 1: pack sign bits of k rows into uint64 bitmasks AND convert k to f16.
// One wave per (b,h,t) row; lane d holds element d. bit=1 iff x>0.
// binary dot = 64 - 2*popc(qm^km).
// ---------------------------------------------------------------------------
__global__ __launch_bounds__(256) void pack_k_kernel(
    const float* __restrict__ k, unsigned long long* __restrict__ kbits,
    _Float16* __restrict__ kh)
{
    int row  = (int)((blockIdx.x * 256 + threadIdx.x) >> 6);
    int lane = (int)(threadIdx.x & 63);
    if (row >= BB * HH * SS) return;
    float kv = k[(size_t)row * DD + lane];
    unsigned long long km = __ballot(kv > 0.0f);
    kh[(size_t)row * DD + lane] = (_Float16)kv;
    if (lane == 0) kbits[row] = km;
}

// ---------------------------------------------------------------------------
// Kernel 2: 256 threads = 4 waves; wave w handles query blockIdx*4+w.
// All 4 queries share the same (b,h) => stage kbits row-block in LDS once.
// Selection threshold via register binary search (no histogram, no atomics).
// ---------------------------------------------------------------------------
__global__ __launch_bounds__(256) void battn_kernel(
    const float* __restrict__ q, const _Float16* __restrict__ kh,
    const float* __restrict__ v, const float* __restrict__ mask,
    const unsigned long long* __restrict__ kbits,
    float* __restrict__ out)
{
    const int tid  = (int)threadIdx.x;
    const int w    = tid >> 6;                    // wave id 0..3
    const int lane = tid & 63;
    const int query = (int)blockIdx.x * QPB + w;  // 0 .. B*H*S-1
    const int bh    = query >> 10;                // S = 1024 (same for all waves)
    const int b     = bh / HH;

    __shared__ unsigned long long kb_sh[SS];      // 8 KB shared by all waves
    __shared__ float        qsh[QPB][DD];
    __shared__ int          sel_t[QPB][KP];
    __shared__ float        sel_p[QPB][KP];
    __shared__ unsigned int nsel[QPB];

    {   // stage kbits (same bh for whole block)
        const unsigned long long* kb = kbits + (size_t)bh * SS;
        #pragma unroll
        for (int it = 0; it < SS / 256; ++it)
            kb_sh[tid + it * 256] = kb[tid + it * 256];
    }
    float qreg = q[(size_t)query * DD + lane];
    qsh[w][lane] = qreg;
    if (lane == 0) nsel[w] = 0u;
    __syncthreads();

    const unsigned long long qm = __ballot(qreg > 0.0f);

    // ---- Phase A: binary-score bins, registers only ----
    int binv[16];
    #pragma unroll
    for (int j = 0; j < 16; ++j)
        binv[j] = 64 - __popcll(qm ^ kb_sh[j * 64 + lane]);   // bin 0..64

    // ---- Phase B: binary search for threshold bin (no LDS, no barrier) ----
    // binT = max{T : count(bin >= T) >= KP}; stable top-k takes all > binT
    // plus first (KP - count(>binT)) ties in ascending key index.
    int lo = 0, hi = 65;
    #pragma unroll 1
    while (hi - lo > 1) {                          // 7 iterations
        int mid = (lo + hi) >> 1;
        int c = 0;
        #pragma unroll
        for (int j = 0; j < 16; ++j) c += (binv[j] >= mid) ? 1 : 0;
        #pragma unroll
        for (int off = 32; off > 0; off >>= 1) c += __shfl_xor(c, off);
        if (c >= KP) lo = mid; else hi = mid;
    }
    const int binT = lo;
    int cgt = 0;
    #pragma unroll
    for (int j = 0; j < 16; ++j) cgt += (binv[j] > binT) ? 1 : 0;
    #pragma unroll
    for (int off = 32; off > 0; off >>= 1) cgt += __shfl_xor(cgt, off);
    const int need = KP - cgt;                     // ties taken, index-asc

    // ---- Phase C1: stable selection (indices only) ----
    int tie_base = 0;
    #pragma unroll
    for (int j = 0; j < 16; ++j) {
        int t = j * 64 + lane;
        bool isGt  = binv[j] > binT;
        bool isTie = (binv[j] == binT);
        unsigned long long tiemask = __ballot(isTie);
        int myrank = tie_base +
            __popcll(tiemask & ((lane == 0) ? 0ULL : (~0ULL >> (64 - lane))));
        if (isGt || (isTie && myrank < need)) {
            unsigned int idx = atomicAdd(&nsel[w], 1u);
            sel_t[w][idx] = t;
        }
        tie_base += (int)__popcll(tiemask);
    }
    __syncthreads();

    // ---- Phase C2: cooperative precise dots, f16 k + v_dot2_f32_f16 ----
    // group g = lane>>3 handles key sel_t[base+g]; lane covers dims sub*8..+8
    const int sub = lane & 7, g = lane >> 3;
    half2v qh[4];
    #pragma unroll
    for (int d = 0; d < 4; ++d) {
        float2 f2 = *(const float2*)&qsh[w][sub * 8 + d * 2];
        half2v h; h[0] = (_Float16)f2.x; h[1] = (_Float16)f2.y;
        qh[d] = h;
    }
    const _Float16* krows  = kh + (size_t)bh * SS * DD;
    const float*   maskrow = mask + (size_t)b * SS;
    #pragma unroll 1
    for (int base = 0; base < KP; base += 8) {
        int i = base + g;
        bool valid = (i < KP);
        float partial = 0.0f;
        int t = 0;
        if (valid) {
            t = sel_t[w][i];
            half8v kv8 = *(const half8v*)(krows + (size_t)t * DD + sub * 8);
            half2v k0; k0[0] = kv8[0]; k0[1] = kv8[1];
            half2v k1; k1[0] = kv8[2]; k1[1] = kv8[3];
            half2v k2; k2[0] = kv8[4]; k2[1] = kv8[5];
            half2v k3; k3[0] = kv8[6]; k3[1] = kv8[7];
            partial = __builtin_amdgcn_fdot2(qh[0], k0, partial, false);
            partial = __builtin_amdgcn_fdot2(qh[1], k1, partial, false);
            partial = __builtin_amdgcn_fdot2(qh[2], k2, partial, false);
            partial = __builtin_amdgcn_fdot2(qh[3], k3, partial, false);
        }
        partial += __shfl_xor(partial, 1);
        partial += __shfl_xor(partial, 2);
        partial += __shfl_xor(partial, 4);
        if (valid && sub == 0)
            sel_p[w][i] = partial * 0.125f + maskrow[t];
    }
    __syncthreads();

    // ---- Phase D: softmax (weights held in regs, 1/lsum folded in) ----
    float p0 = sel_p[w][lane];                               // lane < 64 < KP
    float p1 = (lane + 64 < KP) ? sel_p[w][lane + 64] : -3.0e38f;
    float m = fmaxf(p0, p1);
    #pragma unroll
    for (int off = 32; off > 0; off >>= 1) m = fmaxf(m, __shfl_xor(m, off));
    float e0 = __expf(p0 - m);
    float e1 = __expf(p1 - m);                               // 0 for invalid
    float lsum = e0 + e1;
    #pragma unroll
    for (int off = 32; off > 0; off >>= 1) lsum += __shfl_xor(lsum, off);
    float rinv = __frcp_rn(lsum);
    sel_p[w][lane] = e0 * rinv;
    if (lane + 64 < KP) sel_p[w][lane + 64] = e1 * rinv;
    __syncthreads();

    // ---- Phase E: output accumulation, coalesced v rows, 8 loads in flight
    const float* vbase = v + (size_t)bh * SS * DD + lane;
    float acc = 0.0f;
    #pragma unroll 1
    for (int i0 = 0; i0 + 8 <= KP; i0 += 8) {
        int   tt[8]; float pp[8];
        #pragma unroll
        for (int j = 0; j < 8; ++j) { tt[j] = sel_t[w][i0 + j]; pp[j] = sel_p[w][i0 + j]; }
        #pragma unroll
        for (int j = 0; j < 8; ++j)
            acc += pp[j] * vbase[(size_t)tt[j] * DD];
    }
    {   // tail: KP % 8 = 6
        constexpr int T0 = (KP / 8) * 8;
        int   tt[KP - T0]; float pp[KP - T0];
        #pragma unroll
        for (int j = 0; j < KP - T0; ++j) { tt[j] = sel_t[w][T0 + j]; pp[j] = sel_p[w][T0 + j]; }
        #pragma unroll
        for (int j = 0; j < KP - T0; ++j)
            acc += pp[j] * vbase[(size_t)tt[j] * DD];
    }
    out[(size_t)query * DD + lane] = acc;
}

extern "C" void kernel_launch(void* const* d_in, const int* in_sizes, int n_in,
                              void* d_out, int out_size, void* d_ws, size_t ws_size,
                              hipStream_t stream) {
    const float* q    = (const float*)d_in[0];
    const float* k    = (const float*)d_in[1];
    const float* v    = (const float*)d_in[2];
    const float* mask = (const float*)d_in[3];
    float* out = (float*)d_out;

    const int rows = BB * HH * SS;                 // 24576
    unsigned long long* kbits = (unsigned long long*)d_ws;
    _Float16* kh = (_Float16*)((char*)d_ws + (size_t)rows * sizeof(unsigned long long));

    pack_k_kernel<<<(rows * 64 + 255) / 256, 256, 0, stream>>>(k, kbits, kh);
    battn_kernel<<<rows / QPB, 256, 0, stream>>>(q, kh, v, mask, kbits, out);
}

// Round 4
// 135.882 us; speedup vs baseline: 2.7024x; 1.0855x over previous
//
#include <hip/hip_runtime.h>
#include <hip/hip_fp16.h>
#include <cstdint>

// Problem constants (B,H,S,D from reference setup_inputs; KP = int(S*0.1))
#define BB 2
#define HH 12
#define SS 1024
#define DD 64
#define KP 102
#define QPB 4   // queries per block (1 wave each; waves fully independent)

typedef _Float16 half2v __attribute__((ext_vector_type(2)));
typedef _Float16 half8v __attribute__((ext_vector_type(8)));

// ---------------- DPP cross-lane helpers (VALU, no LDS) ---------------------
// quad_perm(1,0,3,2)=0xB1 (xor1), quad_perm(2,3,0,1)=0x4E (xor2),
// ROW_HALF_MIRROR=0x141 (xor4-equivalent after xor1/xor2),
// ROW_MIRROR=0x140 (xor8-equivalent after the first three).
template <int CTRL>
__device__ __forceinline__ float dpp_f(float x) {
    return __builtin_bit_cast(float,
        __builtin_amdgcn_update_dpp(0, __builtin_bit_cast(int, x), CTRL, 0xF, 0xF, false));
}
__device__ __forceinline__ float readlane_f(float x, int l) {
    return __builtin_bit_cast(float,
        __builtin_amdgcn_readlane(__builtin_bit_cast(int, x), l));
}
// sum over 8-lane group (lanes g*8..g*8+7 all get the group sum)
__device__ __forceinline__ float group8_sum(float x) {
    x += dpp_f<0xB1>(x);
    x += dpp_f<0x4E>(x);
    x += dpp_f<0x141>(x);
    return x;
}
// full-wave sum / max: 4 DPP steps reduce each 16-row, then combine 4 rows
__device__ __forceinline__ float wave_sum_f32(float x) {
    x += dpp_f<0xB1>(x);
    x += dpp_f<0x4E>(x);
    x += dpp_f<0x141>(x);
    x += dpp_f<0x140>(x);
    return (readlane_f(x, 0) + readlane_f(x, 16))
         + (readlane_f(x, 32) + readlane_f(x, 48));
}
__device__ __forceinline__ float wave_max_f32(float x) {
    x = fmaxf(x, dpp_f<0xB1>(x));
    x = fmaxf(x, dpp_f<0x4E>(x));
    x = fmaxf(x, dpp_f<0x141>(x));
    x = fmaxf(x, dpp_f<0x140>(x));
    return fmaxf(fmaxf(readlane_f(x, 0), readlane_f(x, 16)),
                 fmaxf(readlane_f(x, 32), readlane_f(x, 48)));
}

// ---------------------------------------------------------------------------
// Kernel 1: pack sign bits of k rows into uint64 bitmasks AND convert k to f16.
// ---------------------------------------------------------------------------
__global__ __launch_bounds__(256) void pack_k_kernel(
    const float* __restrict__ k, unsigned long long* __restrict__ kbits,
    _Float16* __restrict__ kh)
{
    int row  = (int)((blockIdx.x * 256 + threadIdx.x) >> 6);
    int lane = (int)(threadIdx.x & 63);
    if (row >= BB * HH * SS) return;
    float kv = k[(size_t)row * DD + lane];
    unsigned long long km = __ballot(kv > 0.0f);
    kh[(size_t)row * DD + lane] = (_Float16)kv;
    if (lane == 0) kbits[row] = km;
}

// ---------------------------------------------------------------------------
// Kernel 2: 256 threads = 4 independent waves; wave w handles query b*4+w.
// No __syncthreads: every LDS array is wave-private (same-wave LDS ordering).
// ---------------------------------------------------------------------------
__global__ __launch_bounds__(256) void battn_kernel(
    const float* __restrict__ q, const _Float16* __restrict__ kh,
    const float* __restrict__ v, const float* __restrict__ mask,
    const unsigned long long* __restrict__ kbits,
    float* __restrict__ out)
{
    const int tid  = (int)threadIdx.x;
    const int w    = tid >> 6;                    // wave id 0..3
    const int lane = tid & 63;
    const int query = (int)blockIdx.x * QPB + w;  // 0 .. B*H*S-1
    const int bh    = query >> 10;                // S = 1024
    const int b     = bh / HH;

    __shared__ int   sel_t[QPB][KP];
    __shared__ float sel_p[QPB][KP];

    const float qreg = q[(size_t)query * DD + lane];
    const unsigned long long qm = __ballot(qreg > 0.0f);

    // ---- Phase A: binary-score bins (register-resident) ----
    const unsigned long long* kb = kbits + (size_t)bh * SS;
    int binv[16];
    #pragma unroll
    for (int j = 0; j < 16; ++j)
        binv[j] = 64 - __popcll(qm ^ kb[j * 64 + lane]);   // 0..64, monotone in dot

    // ---- Phase B: threshold via binary search; counts are ballot+popc
    //      (wave-uniform scalar, no cross-lane reduce needed) ----
    int lo = 0, hi = 65;
    #pragma unroll 1
    while (hi - lo > 1) {                          // 7 iterations
        int mid = (lo + hi) >> 1;
        int c = 0;
        #pragma unroll
        for (int j = 0; j < 16; ++j)
            c += (int)__popcll(__ballot(binv[j] >= mid));
        if (c >= KP) lo = mid; else hi = mid;
    }
    const int binT = lo;
    int cgt = 0;
    #pragma unroll
    for (int j = 0; j < 16; ++j)
        cgt += (int)__popcll(__ballot(binv[j] > binT));
    const int need = KP - cgt;                     // ties taken, index-asc

    // ---- Phase C1: stable selection, ballot-prefix compaction (no atomics)
    const unsigned long long lmask_lt = (lane == 0) ? 0ULL : (~0ULL >> (64 - lane));
    int base = 0, tie_base = 0;
    #pragma unroll
    for (int j = 0; j < 16; ++j) {
        bool isGt  = binv[j] > binT;
        bool isTie = (binv[j] == binT);
        unsigned long long tiem = __ballot(isTie);
        int rank = tie_base + (int)__popcll(tiem & lmask_lt);
        bool take = isGt || (isTie && rank < need);
        unsigned long long tm = __ballot(take);
        if (take)
            sel_t[w][base + (int)__popcll(tm & lmask_lt)] = j * 64 + lane;
        base     += (int)__popcll(tm);
        tie_base += (int)__popcll(tiem);
    }

    // ---- Phase C2: cooperative precise dots, f16 k + v_dot2_f32_f16 ----
    // group g = lane>>3 handles key sel_t[base+g]; lane covers dims sub*8..+8
    const int sub = lane & 7, g = lane >> 3;
    const float* qrow = q + (size_t)query * DD + sub * 8;
    half2v qh[4];
    #pragma unroll
    for (int d = 0; d < 4; ++d) {
        float2 f2 = *(const float2*)(qrow + d * 2);
        half2v h; h[0] = (_Float16)f2.x; h[1] = (_Float16)f2.y;
        qh[d] = h;
    }
    const _Float16* krows = kh + (size_t)bh * SS * DD;
    #pragma unroll 1
    for (int i0 = 0; i0 < KP; i0 += 8) {
        int i = i0 + g;
        bool valid = (i < KP);
        float partial = 0.0f;
        if (valid) {
            int t = sel_t[w][i];
            half8v kv8 = *(const half8v*)(krows + (size_t)t * DD + sub * 8);
            half2v k0; k0[0] = kv8[0]; k0[1] = kv8[1];
            half2v k1; k1[0] = kv8[2]; k1[1] = kv8[3];
            half2v k2; k2[0] = kv8[4]; k2[1] = kv8[5];
            half2v k3; k3[0] = kv8[6]; k3[1] = kv8[7];
            partial = __builtin_amdgcn_fdot2(qh[0], k0, partial, false);
            partial = __builtin_amdgcn_fdot2(qh[1], k1, partial, false);
            partial = __builtin_amdgcn_fdot2(qh[2], k2, partial, false);
            partial = __builtin_amdgcn_fdot2(qh[3], k3, partial, false);
        }
        partial = group8_sum(partial);
        if (valid && sub == 0)
            sel_p[w][i] = partial * 0.125f;
    }

    // ---- Phase D: softmax; weights end up register-distributed (2/lane) ----
    const float* maskrow = mask + (size_t)b * SS;
    const bool has2 = (lane < KP - 64);                     // entries 64..101
    int   t0 = sel_t[w][lane];
    int   t1 = has2 ? sel_t[w][lane + 64] : 0;
    float p0 = sel_p[w][lane] + maskrow[t0];
    float p1 = has2 ? (sel_p[w][lane + 64] + maskrow[t1]) : -3.0e38f;
    float m  = wave_max_f32(fmaxf(p0, p1));
    float e0 = __expf(p0 - m);
    float e1 = has2 ? __expf(p1 - m) : 0.0f;
    float rinv = __frcp_rn(wave_sum_f32(e0 + e1));
    float w0 = e0 * rinv;
    float w1 = e1 * rinv;

    // ---- Phase E: output accumulation; per-key (t,p) broadcast via readlane
    //      -> SGPR row base + v_fmac with SGPR weight; coalesced 256B rows ---
    const float* vbase = v + (size_t)bh * SS * DD + lane;
    float acc0 = 0.0f, acc1 = 0.0f;
    #pragma unroll
    for (int i = 0; i < 64; i += 2) {
        int   ta = __builtin_amdgcn_readlane(t0, i);
        float pa = readlane_f(w0, i);
        int   tb = __builtin_amdgcn_readlane(t0, i + 1);
        float pb = readlane_f(w0, i + 1);
        acc0 = fmaf(pa, vbase[(size_t)ta * DD], acc0);
        acc1 = fmaf(pb, vbase[(size_t)tb * DD], acc1);
    }
    #pragma unroll
    for (int i = 0; i < KP - 64; i += 2) {                  // 38 entries
        int   ta = __builtin_amdgcn_readlane(t1, i);
        float pa = readlane_f(w1, i);
        int   tb = __builtin_amdgcn_readlane(t1, i + 1);
        float pb = readlane_f(w1, i + 1);
        acc0 = fmaf(pa, vbase[(size_t)ta * DD], acc0);
        acc1 = fmaf(pb, vbase[(size_t)tb * DD], acc1);
    }
    out[(size_t)query * DD + lane] = acc0 + acc1;
}

extern "C" void kernel_launch(void* const* d_in, const int* in_sizes, int n_in,
                              void* d_out, int out_size, void* d_ws, size_t ws_size,
                              hipStream_t stream) {
    const float* q    = (const float*)d_in[0];
    const float* k    = (const float*)d_in[1];
    const float* v    = (const float*)d_in[2];
    const float* mask = (const float*)d_in[3];
    float* out = (float*)d_out;

    const int rows = BB * HH * SS;                 // 24576
    unsigned long long* kbits = (unsigned long long*)d_ws;
    _Float16* kh = (_Float16*)((char*)d_ws + (size_t)rows * sizeof(unsigned long long));

    pack_k_kernel<<<(rows * 64 + 255) / 256, 256, 0, stream>>>(k, kbits, kh);
    battn_kernel<<<rows / QPB, 256, 0, stream>>>(q, kh, v, mask, kbits, out);
}

// Round 5
// 120.167 us; speedup vs baseline: 3.0558x; 1.1308x over previous
//
#include <hip/hip_runtime.h>
#include <hip/hip_fp16.h>
#include <cstdint>

// Problem constants (B,H,S,D from reference setup_inputs; KP = int(S*0.1))
#define BB 2
#define HH 12
#define SS 1024
#define DD 64
#define KP 102
#define KPAD 104  // pad so tail lanes may write harmlessly
#define QPB 4     // queries per block (1 wave each; waves fully independent)

typedef _Float16 half2v __attribute__((ext_vector_type(2)));
typedef _Float16 half8v __attribute__((ext_vector_type(8)));

// ---------------- DPP / cross-lane helpers (VALU, no LDS arrays) ------------
template <int CTRL>
__device__ __forceinline__ float dpp_f(float x) {
    return __builtin_bit_cast(float,
        __builtin_amdgcn_update_dpp(0, __builtin_bit_cast(int, x), CTRL, 0xF, 0xF, false));
}
__device__ __forceinline__ float readlane_f(float x, int l) {
    return __builtin_bit_cast(float,
        __builtin_amdgcn_readlane(__builtin_bit_cast(int, x), l));
}
__device__ __forceinline__ int bperm_i(int addr4, int src) {
    return __builtin_amdgcn_ds_bpermute(addr4, src);
}
__device__ __forceinline__ float bperm_f(int addr4, float src) {
    return __builtin_bit_cast(float,
        __builtin_amdgcn_ds_bpermute(addr4, __builtin_bit_cast(int, src)));
}
// sum over 8-lane group (all 8 lanes get the group sum)
__device__ __forceinline__ float group8_sum(float x) {
    x += dpp_f<0xB1>(x);      // quad_perm xor1
    x += dpp_f<0x4E>(x);      // quad_perm xor2
    x += dpp_f<0x141>(x);     // row_half_mirror (xor4)
    return x;
}
__device__ __forceinline__ float wave_sum_f32(float x) {
    x += dpp_f<0xB1>(x);
    x += dpp_f<0x4E>(x);
    x += dpp_f<0x141>(x);
    x += dpp_f<0x140>(x);     // row_mirror (xor8)
    return (readlane_f(x, 0) + readlane_f(x, 16))
         + (readlane_f(x, 32) + readlane_f(x, 48));
}
__device__ __forceinline__ float wave_max_f32(float x) {
    x = fmaxf(x, dpp_f<0xB1>(x));
    x = fmaxf(x, dpp_f<0x4E>(x));
    x = fmaxf(x, dpp_f<0x141>(x));
    x = fmaxf(x, dpp_f<0x140>(x));
    return fmaxf(fmaxf(readlane_f(x, 0), readlane_f(x, 16)),
                 fmaxf(readlane_f(x, 32), readlane_f(x, 48)));
}

// ---------------------------------------------------------------------------
// Kernel 1: pack sign bits of k rows -> uint64; convert k and v rows to f16.
// ---------------------------------------------------------------------------
__global__ __launch_bounds__(256) void pack_kernel(
    const float* __restrict__ k, const float* __restrict__ v,
    unsigned long long* __restrict__ kbits,
    _Float16* __restrict__ kh, _Float16* __restrict__ vh)
{
    int row  = (int)((blockIdx.x * 256 + threadIdx.x) >> 6);
    int lane = (int)(threadIdx.x & 63);
    if (row >= BB * HH * SS) return;
    float kv = k[(size_t)row * DD + lane];
    float vv = v[(size_t)row * DD + lane];
    unsigned long long km = __ballot(kv > 0.0f);
    kh[(size_t)row * DD + lane] = (_Float16)kv;
    vh[(size_t)row * DD + lane] = (_Float16)vv;
    if (lane == 0) kbits[row] = km;
}

// ---------------------------------------------------------------------------
// Kernel 2: 256 threads = 4 independent waves; wave w handles query blk*4+w.
// No __syncthreads: all LDS arrays are wave-private (same-wave LDS ordering).
// ---------------------------------------------------------------------------
__global__ __launch_bounds__(256, 4) void battn_kernel(
    const float* __restrict__ q, const _Float16* __restrict__ kh,
    const _Float16* __restrict__ vh, const float* __restrict__ mask,
    const unsigned long long* __restrict__ kbits,
    float* __restrict__ out)
{
    const int tid  = (int)threadIdx.x;
    const int w    = tid >> 6;                    // wave id 0..3
    const int lane = tid & 63;
    const int query = (int)blockIdx.x * QPB + w;  // 0 .. B*H*S-1
    const int bh    = query >> 10;                // S = 1024
    const int b     = bh / HH;

    __shared__ int   sel_t[QPB][KPAD];
    __shared__ float sel_p[QPB][KPAD];

    const float qreg = q[(size_t)query * DD + lane];
    const unsigned long long qm = __ballot(qreg > 0.0f);

    // ---- Phase A: binary-score bins (register-resident) ----
    const unsigned long long* kb = kbits + (size_t)bh * SS;
    int binv[16];
    #pragma unroll
    for (int j = 0; j < 16; ++j)
        binv[j] = 64 - __popcll(qm ^ kb[j * 64 + lane]);   // 0..64, monotone in dot

    // ---- Phase B: threshold via binary search; counts via ballot+popc ----
    int lo = 0, hi = 65;
    #pragma unroll 1
    while (hi - lo > 1) {                          // 7 iterations
        int mid = (lo + hi) >> 1;
        int c = 0;
        #pragma unroll
        for (int j = 0; j < 16; ++j)
            c += (int)__popcll(__ballot(binv[j] >= mid));
        if (c >= KP) lo = mid; else hi = mid;
    }
    const int binT = lo;
    int cgt = 0;
    #pragma unroll
    for (int j = 0; j < 16; ++j)
        cgt += (int)__popcll(__ballot(binv[j] > binT));
    const int need = KP - cgt;                     // ties taken, index-asc

    // ---- Phase C1: stable selection, ballot-prefix compaction ----
    const unsigned long long lmask_lt = (lane == 0) ? 0ULL : (~0ULL >> (64 - lane));
    int base = 0, tie_base = 0;
    #pragma unroll
    for (int j = 0; j < 16; ++j) {
        bool isGt  = binv[j] > binT;
        bool isTie = (binv[j] == binT);
        unsigned long long tiem = __ballot(isTie);
        int rank = tie_base + (int)__popcll(tiem & lmask_lt);
        bool take = isGt || (isTie && rank < need);
        unsigned long long tm = __ballot(take);
        if (take)
            sel_t[w][base + (int)__popcll(tm & lmask_lt)] = j * 64 + lane;
        base     += (int)__popcll(tm);
        tie_base += (int)__popcll(tiem);
    }

    // register-distribute indices: lane l holds keys l and l+64
    const int t0 = sel_t[w][lane];
    const int t1 = (lane < KP - 64) ? sel_t[w][lane + 64] : 0;  // 0 = safe row

    // ---- Phase C2: cooperative precise dots, fully pipelined ----
    // group g = lane>>3 handles key i0+g; lane covers dims sub*8..sub*8+8.
    // t fetched from registers via bpermute -> no LDS->VMEM serial chain.
    const int sub = lane & 7, g = lane >> 3;
    const float* qrow = q + (size_t)query * DD + sub * 8;
    half2v qh[4];
    #pragma unroll
    for (int d = 0; d < 4; ++d) {
        float2 f2 = *(const float2*)(qrow + d * 2);
        half2v h; h[0] = (_Float16)(f2.x * 0.125f); h[1] = (_Float16)(f2.y * 0.125f);
        qh[d] = h;                                  // scale folded into q
    }
    const _Float16* krows = kh + (size_t)bh * SS * DD;
    #pragma unroll
    for (int i0 = 0; i0 < KP; i0 += 8) {           // 13 independent iterations
        const int addr = ((i0 & 63) + g) << 2;
        int t = bperm_i(addr, (i0 < 64) ? t0 : t1);
        half8v kv8 = *(const half8v*)(krows + (size_t)t * DD + sub * 8);
        half2v k0; k0[0] = kv8[0]; k0[1] = kv8[1];
        half2v k1; k1[0] = kv8[2]; k1[1] = kv8[3];
        half2v k2; k2[0] = kv8[4]; k2[1] = kv8[5];
        half2v k3; k3[0] = kv8[6]; k3[1] = kv8[7];
        float partial = __builtin_amdgcn_fdot2(qh[0], k0, 0.0f, false);
        partial = __builtin_amdgcn_fdot2(qh[1], k1, partial, false);
        partial = __builtin_amdgcn_fdot2(qh[2], k2, partial, false);
        partial = __builtin_amdgcn_fdot2(qh[3], k3, partial, false);
        partial = group8_sum(partial);
        if (sub == 0) sel_p[w][i0 + g] = partial;  // i0+g <= 103 < KPAD
    }

    // ---- Phase D: softmax; weights register-distributed (2/lane) ----
    const float* maskrow = mask + (size_t)b * SS;
    const bool has2 = (lane < KP - 64);
    float p0 = sel_p[w][lane] + maskrow[t0];
    float p1 = has2 ? (sel_p[w][lane + 64] + maskrow[t1]) : -3.0e38f;
    float m  = wave_max_f32(fmaxf(p0, p1));
    float e0 = __expf(p0 - m);
    float e1 = has2 ? __expf(p1 - m) : 0.0f;       // 0 weight for pad keys
    float rinv = __frcp_rn(wave_sum_f32(e0 + e1));
    float w0 = e0 * rinv;
    float w1 = e1 * rinv;                          // 0 for lanes >= 38

    // ---- Phase E: output accumulation, same 8-lane-per-key structure ----
    // 13 independent 1KB loads of f16 v rows; weight via bpermute; per-lane
    // acc[8] over dims sub*8..+8; cross-group xor-reduce; 8-lane f4 store.
    const _Float16* vrows = vh + (size_t)bh * SS * DD;
    float acc[8] = {0.f, 0.f, 0.f, 0.f, 0.f, 0.f, 0.f, 0.f};
    #pragma unroll
    for (int i0 = 0; i0 < KP; i0 += 8) {           // 13 independent iterations
        const int addr = ((i0 & 63) + g) << 2;
        int   t  = bperm_i(addr, (i0 < 64) ? t0 : t1);
        float wt = bperm_f(addr, (i0 < 64) ? w0 : w1);   // 0 for pad keys
        half8v vv = *(const half8v*)(vrows + (size_t)t * DD + sub * 8);
        #pragma unroll
        for (int d = 0; d < 8; ++d)
            acc[d] = fmaf(wt, (float)vv[d], acc[d]);
    }
    #pragma unroll
    for (int d = 0; d < 8; ++d) {                  // reduce across the 8 groups
        float x = acc[d];
        x += __shfl_xor(x, 8);
        x += __shfl_xor(x, 16);
        x += __shfl_xor(x, 32);
        acc[d] = x;
    }
    if (lane < 8) {                                // g==0, sub==lane
        float* orow = out + (size_t)query * DD + lane * 8;
        float4 o0 = make_float4(acc[0], acc[1], acc[2], acc[3]);
        float4 o1 = make_float4(acc[4], acc[5], acc[6], acc[7]);
        *(float4*)orow       = o0;
        *(float4*)(orow + 4) = o1;
    }
}

extern "C" void kernel_launch(void* const* d_in, const int* in_sizes, int n_in,
                              void* d_out, int out_size, void* d_ws, size_t ws_size,
                              hipStream_t stream) {
    const float* q    = (const float*)d_in[0];
    const float* k    = (const float*)d_in[1];
    const float* v    = (const float*)d_in[2];
    const float* mask = (const float*)d_in[3];
    float* out = (float*)d_out;

    const int rows = BB * HH * SS;                 // 24576
    unsigned long long* kbits = (unsigned long long*)d_ws;
    _Float16* kh = (_Float16*)((char*)d_ws + (size_t)rows * sizeof(unsigned long long));
    _Float16* vh = kh + (size_t)rows * DD;

    pack_kernel<<<(rows * 64 + 255) / 256, 256, 0, stream>>>(k, v, kbits, kh, vh);
    battn_kernel<<<rows / QPB, 256, 0, stream>>>(q, kh, vh, mask, kbits, out);
}